// Round 1
// baseline (150.249 us; speedup 1.0000x reference)
//
#include <hip/hip_runtime.h>

#define IN_DIM  128
#define OUT_DIM 64
#define DEG     32
#define NEG_SLOPE 0.01f

// ---------------------------------------------------------------------------
// Kernel 1: z = feat @ W   [n,128]x[128,64] -> [n,64]  (f32 vector math;
// CDNA4 has no fp32-input MFMA).  Also s[n] = z[n]·aw[0:64], t[n] = z[n]·aw[64:128].
// One wave handles 4 rows per iteration, sharing the LDS reads of W.
// Feature rows are wave-uniform -> scalar (s_load) path via readfirstlane.
// ---------------------------------------------------------------------------
__global__ __launch_bounds__(256) void cgat_fc(
    const float* __restrict__ feat,   // [n*128]
    const float* __restrict__ W,      // [128*64] row-major (k, d)
    const float* __restrict__ aw,     // [128]
    float* __restrict__ z,            // [n*64]
    float* __restrict__ s,            // [n]
    float* __restrict__ t,            // [n]
    int n)
{
    __shared__ float Wl[IN_DIM * OUT_DIM];   // 32 KB
    {
        const float4* W4  = (const float4*)W;
        float4*       Wl4 = (float4*)Wl;
        #pragma unroll
        for (int i = 0; i < (IN_DIM * OUT_DIM / 4) / 256; ++i)
            Wl4[i * 256 + threadIdx.x] = W4[i * 256 + threadIdx.x];
    }
    __syncthreads();

    const int   lane = threadIdx.x & 63;
    const float a_s  = aw[lane];
    const float a_t  = aw[OUT_DIM + lane];

    const int gw = blockIdx.x * 4 + (threadIdx.x >> 6);  // global wave id
    const int nw = gridDim.x * 4;

    for (int r0 = gw * 4; r0 < n; r0 += nw * 4) {
        const int r  = __builtin_amdgcn_readfirstlane(r0);  // force SGPR -> s_load path
        const int r1 = min(r + 1, n - 1);
        const int r2 = min(r + 2, n - 1);
        const int r3 = min(r + 3, n - 1);
        const float* __restrict__ f0 = feat + (size_t)r  * IN_DIM;
        const float* __restrict__ f1 = feat + (size_t)r1 * IN_DIM;
        const float* __restrict__ f2 = feat + (size_t)r2 * IN_DIM;
        const float* __restrict__ f3 = feat + (size_t)r3 * IN_DIM;

        float acc0 = 0.f, acc1 = 0.f, acc2 = 0.f, acc3 = 0.f;
        #pragma unroll 16
        for (int k = 0; k < IN_DIM; ++k) {
            const float wv = Wl[k * OUT_DIM + lane];   // 2 lanes/bank: conflict-free
            acc0 = fmaf(f0[k], wv, acc0);
            acc1 = fmaf(f1[k], wv, acc1);
            acc2 = fmaf(f2[k], wv, acc2);
            acc3 = fmaf(f3[k], wv, acc3);
        }

        z[(size_t)r  * OUT_DIM + lane] = acc0;
        z[(size_t)r1 * OUT_DIM + lane] = acc1;
        z[(size_t)r2 * OUT_DIM + lane] = acc2;
        z[(size_t)r3 * OUT_DIM + lane] = acc3;

        float sv0 = acc0 * a_s, tv0 = acc0 * a_t;
        float sv1 = acc1 * a_s, tv1 = acc1 * a_t;
        float sv2 = acc2 * a_s, tv2 = acc2 * a_t;
        float sv3 = acc3 * a_s, tv3 = acc3 * a_t;
        #pragma unroll
        for (int off = 32; off > 0; off >>= 1) {
            sv0 += __shfl_xor(sv0, off, 64); tv0 += __shfl_xor(tv0, off, 64);
            sv1 += __shfl_xor(sv1, off, 64); tv1 += __shfl_xor(tv1, off, 64);
            sv2 += __shfl_xor(sv2, off, 64); tv2 += __shfl_xor(tv2, off, 64);
            sv3 += __shfl_xor(sv3, off, 64); tv3 += __shfl_xor(tv3, off, 64);
        }
        if (lane == 0) {
            s[r] = sv0; s[r1] = sv1; s[r2] = sv2; s[r3] = sv3;
            t[r] = tv0; t[r1] = tv1; t[r2] = tv2; t[r3] = tv3;
        }
    }
}

// ---------------------------------------------------------------------------
// Kernel 2: per node n (one wave each):
//   e_j     = leaky_relu(s[idx[n,j]] + t[n]),            j = 0..31
//   alpha_j = sum_k max(e_j - e_k, 0)
//   h[n,d]  = sum_j alpha_j * z[idx[n,j]][d],            lane d = 0..63
// Per-j scalars broadcast with v_readlane (compile-time lane index) ->
// alpha_j / idx_j land in SGPRs; gather becomes global_load_dword v, voff, s[base].
// ---------------------------------------------------------------------------
__global__ __launch_bounds__(256) void cgat_gather(
    const int*   __restrict__ idx,    // [n*32]
    const float* __restrict__ z,      // [n*64]
    const float* __restrict__ s,      // [n]
    const float* __restrict__ t,      // [n]
    float* __restrict__ h,            // [n*64]
    int n)
{
    const int lane = threadIdx.x & 63;
    int node = blockIdx.x * 4 + (threadIdx.x >> 6);
    if (node >= n) return;
    node = __builtin_amdgcn_readfirstlane(node);

    const int   j  = lane & 31;                       // upper 32 lanes duplicate
    const int   ij = idx[(size_t)node * DEG + j];     // one 128B segment per wave
    const float tn = t[node];

    float e = s[ij] + tn;                             // random 4B gather, 200KB table (L2-hot)
    e = (e >= 0.f) ? e : NEG_SLOPE * e;

    // alpha_j = sum_k max(e_j - e_k, 0)
    float alpha = 0.f;
    #pragma unroll
    for (int k = 0; k < DEG; ++k) {
        const float ek = __int_as_float(__builtin_amdgcn_readlane(__float_as_int(e), k));
        alpha += fmaxf(e - ek, 0.f);
    }

    // h[node, lane] = sum_j alpha_j * z[idx_j, lane]
    float hd = 0.f;
    #pragma unroll
    for (int k = 0; k < DEG; ++k) {
        const float ak = __int_as_float(__builtin_amdgcn_readlane(__float_as_int(alpha), k));
        const int   ik = __builtin_amdgcn_readlane(ij, k);
        hd = fmaf(ak, z[(size_t)ik * OUT_DIM + lane], hd);   // coalesced 256B row gather
    }
    h[(size_t)node * OUT_DIM + lane] = hd;
}

// ---------------------------------------------------------------------------
extern "C" void kernel_launch(void* const* d_in, const int* in_sizes, int n_in,
                              void* d_out, int out_size, void* d_ws, size_t ws_size,
                              hipStream_t stream)
{
    const float* feat = (const float*)d_in[0];   // [N,128] f32
    const int*   idx  = (const int*)  d_in[1];   // [N,32]  i32
    const float* W    = (const float*)d_in[2];   // [128,64] f32
    const float* aw   = (const float*)d_in[3];   // [128,1] f32
    float*       h    = (float*)d_out;           // [N,64] f32

    const int n = in_sizes[0] / IN_DIM;

    // workspace: z [n*64] f32, s [n] f32, t [n] f32  (≈13.2 MB, fully rewritten each launch)
    float* z = (float*)d_ws;
    float* s = z + (size_t)n * OUT_DIM;
    float* t = s + n;

    cgat_fc<<<800, 256, 0, stream>>>(feat, W, aw, z, s, t, n);

    const int blocks = (n + 3) / 4;   // one wave per node, 4 waves/block
    cgat_gather<<<blocks, 256, 0, stream>>>(idx, z, s, t, h, n);
}